// Round 1
// baseline (16620.781 us; speedup 1.0000x reference)
//
#include <hip/hip_runtime.h>
#include <hip/hip_cooperative_groups.h>

namespace cg = cooperative_groups;

#define N_NODES 4096
#define H_DIM 32
#define F_INPUT 5
#define ROLLS 200

typedef __attribute__((ext_vector_type(8))) short bf16x8;
typedef __attribute__((ext_vector_type(4))) float fx4;

__device__ __forceinline__ unsigned short f2bf(float f) {
  unsigned int u = __builtin_bit_cast(unsigned int, f);
  u += 0x7fffu + ((u >> 16) & 1u);   // round-to-nearest-even (inputs are benign, no NaN/inf)
  return (unsigned short)(u >> 16);
}

// Persistent cooperative kernel: all 200 recurrence steps in one launch.
// grid = 256 blocks (1/CU), block = 512 threads (8 waves), 16 rows per block.
// A lives in VGPRs (64 regs/lane = the whole 32 MiB across the chip).
// h/c live in LDS. Mt (= x@Wx + h@Wh + c@Wc, transposed bf16) is the only
// cross-block state: triple-buffered in global, one grid.sync() per step.
__global__ __launch_bounds__(512, 2) void k_roll(
    const float* __restrict__ A, const float* __restrict__ X,
    const float* __restrict__ Wx, const float* __restrict__ Wh, const float* __restrict__ Wc,
    const float* __restrict__ Wih, const float* __restrict__ Whh,
    const float* __restrict__ b_ih, const float* __restrict__ b_hh,
    const float* __restrict__ Wfc, const float* __restrict__ b_fc,
    float* __restrict__ out,
    unsigned short* __restrict__ buf0, unsigned short* __restrict__ buf1,
    unsigned short* __restrict__ buf2) {

  cg::grid_group grid = cg::this_grid();

  __shared__ __align__(16) float red[8 * 16 * 33];          // split-K partials (pad 33)
  __shared__ __align__(16) unsigned short inpB[16 * 48];    // inp bf16, A-frag layout
  __shared__ __align__(16) unsigned short hB[16 * 48];      // persistent h (bf16 frag)
  __shared__ __align__(16) unsigned short cnB[16 * 48];     // c_new bf16 (for M_next)
  __shared__ __align__(16) unsigned short MnB[16 * 48];
  __shared__ __align__(16) float cB[16 * 32];               // persistent c (fp32)
  __shared__ __align__(16) float gatesLds[16 * 132];
  __shared__ __align__(16) float xLds[16 * 8];

  const int tid  = threadIdx.x;
  const int wave = tid >> 6;        // 0..7
  const int lane = tid & 63;
  const int l15  = lane & 15;
  const int quad = lane >> 4;       // 0..3
  const int row0 = blockIdx.x << 4;

  // ---- prologue: A fragments fp32->bf16 into VGPRs (once) ----
  bf16x8 areg[16];
  {
    const float* Ap = A + (size_t)(row0 + l15) * N_NODES + wave * 512 + quad * 8;
#pragma unroll
    for (int kk = 0; kk < 16; ++kk) {
      bf16x8 a;
#pragma unroll
      for (int j = 0; j < 8; ++j) a[j] = (short)f2bf(Ap[kk * 32 + j]);
      areg[kk] = a;
    }
  }

  // gate weight fragments: wave w owns gate cols [16w, 16w+16)
  const int g = (wave << 4) + l15;
  bf16x8 bI, bH;
#pragma unroll
  for (int j = 0; j < 8; ++j) {
    bI[j] = (short)f2bf(Wih[g * 32 + quad * 8 + j]);
    bH[j] = (short)f2bf(Whh[g * 32 + quad * 8 + j]);
  }
  const float bias = b_ih[g] + b_hh[g];

  // M_next weight fragments (waves 0,1 only): WhT[n][k]=Wh[k][n]
  bf16x8 bWh, bWc;
  float wx5[F_INPUT];
  if (wave < 2) {
#pragma unroll
    for (int j = 0; j < 8; ++j) {
      bWh[j] = (short)f2bf(Wh[(quad * 8 + j) * H_DIM + g]);
      bWc[j] = (short)f2bf(Wc[(quad * 8 + j) * H_DIM + g]);
    }
#pragma unroll
    for (int f = 0; f < F_INPUT; ++f) wx5[f] = Wx[f * H_DIM + g];
  }

  // h = c = 0 ; Mt0 = (x0 @ Wx)^T bf16
  {
    int r = tid >> 5, k = tid & 31;
    hB[r * 48 + k] = 0;       // f2bf(0)==0
    cB[r * 32 + k] = 0.f;
    float s = 0.f;
#pragma unroll
    for (int f = 0; f < F_INPUT; ++f)
      s += X[(size_t)(row0 + r) * F_INPUT + f] * Wx[f * H_DIM + k];
    buf0[(size_t)k * N_NODES + row0 + r] = f2bf(s);
  }
  __threadfence();
  grid.sync();

  unsigned short* m0 = buf0;   // read at step t
  unsigned short* m1 = buf1;   // written at step t
  unsigned short* m2 = buf2;   // idle at step t

  for (int t = 0; t < ROLLS; ++t) {
    // ---- phase A: split-K MFMA inp(16x32) = A(16x4096) @ M(4096x32) ----
    fx4 acc0 = {0.f, 0.f, 0.f, 0.f}, acc1 = {0.f, 0.f, 0.f, 0.f};
    {
      const unsigned short* B0 = m0 + (size_t)l15 * N_NODES + wave * 512 + quad * 8;
      const unsigned short* B1 = B0 + (size_t)16 * N_NODES;
#pragma unroll
      for (int kk = 0; kk < 16; ++kk) {
        bf16x8 b0 = *(const bf16x8*)(B0 + kk * 32);
        bf16x8 b1 = *(const bf16x8*)(B1 + kk * 32);
        acc0 = __builtin_amdgcn_mfma_f32_16x16x32_bf16(areg[kk], b0, acc0, 0, 0, 0);
        acc1 = __builtin_amdgcn_mfma_f32_16x16x32_bf16(areg[kk], b1, acc1, 0, 0, 0);
      }
    }
#pragma unroll
    for (int r = 0; r < 4; ++r) {
      red[(wave * 16 + quad * 4 + r) * 33 + l15]      = acc0[r];
      red[(wave * 16 + quad * 4 + r) * 33 + 16 + l15] = acc1[r];
    }
    __syncthreads();

    // ---- phase B: reduce 8 partials -> inp bf16 ; stage x_{t+1} ----
    {
      int m = tid >> 5, n = tid & 31;
      float s = 0.f;
#pragma unroll
      for (int w = 0; w < 8; ++w) s += red[(w * 16 + m) * 33 + n];
      inpB[m * 48 + n] = f2bf(s);
    }
    if (t + 1 < ROLLS && tid < 128) {
      int r = tid >> 3, f = tid & 7;
      if (f < F_INPUT)
        xLds[r * 8 + f] = X[(size_t)(t + 1) * N_NODES * F_INPUT +
                            (size_t)(row0 + r) * F_INPUT + f];
    }
    __syncthreads();

    // ---- phase C: gates(16x128) = inp@Wih^T + h@Whh^T + b ----
    {
      bf16x8 aI = *(const bf16x8*)(inpB + l15 * 48 + quad * 8);
      bf16x8 aH = *(const bf16x8*)(hB   + l15 * 48 + quad * 8);
      fx4 gacc = {0.f, 0.f, 0.f, 0.f};
      gacc = __builtin_amdgcn_mfma_f32_16x16x32_bf16(aI, bI, gacc, 0, 0, 0);
      gacc = __builtin_amdgcn_mfma_f32_16x16x32_bf16(aH, bH, gacc, 0, 0, 0);
#pragma unroll
      for (int r = 0; r < 4; ++r) gatesLds[(quad * 4 + r) * 132 + g] = gacc[r] + bias;
    }
    __syncthreads();

    // ---- phase D: LSTM cell elementwise (fp32 state in LDS) ----
    {
      int r = tid >> 5, k = tid & 31;
      float gi = gatesLds[r * 132 + k];
      float gf = gatesLds[r * 132 + 32 + k];
      float gg = gatesLds[r * 132 + 64 + k];
      float go = gatesLds[r * 132 + 96 + k];
      float i_ = 1.f / (1.f + __expf(-gi));
      float f_ = 1.f / (1.f + __expf(-gf));
      float g_ = tanhf(gg);
      float o_ = 1.f / (1.f + __expf(-go));
      float cn = f_ * cB[r * 32 + k] + i_ * g_;
      float hn = o_ * tanhf(cn);
      cB[r * 32 + k] = cn;
      hB[r * 48 + k] = f2bf(hn);        // becomes next step's h fragment
      cnB[r * 48 + k] = f2bf(cn);
      if (t == ROLLS - 1) gatesLds[r * 132 + k] = hn * Wfc[k];
    }
    __syncthreads();

    // ---- phase E: M_next = h@Wh + c@Wc + x@Wx (waves 0,1), transposed write ----
    if (t < ROLLS - 1) {
      if (wave < 2) {
        bf16x8 aH = *(const bf16x8*)(hB  + l15 * 48 + quad * 8);
        bf16x8 aC = *(const bf16x8*)(cnB + l15 * 48 + quad * 8);
        fx4 m4 = {0.f, 0.f, 0.f, 0.f};
        m4 = __builtin_amdgcn_mfma_f32_16x16x32_bf16(aH, bWh, m4, 0, 0, 0);
        m4 = __builtin_amdgcn_mfma_f32_16x16x32_bf16(aC, bWc, m4, 0, 0, 0);
#pragma unroll
        for (int r = 0; r < 4; ++r) {
          int m = quad * 4 + r;
          float xs = m4[r];
#pragma unroll
          for (int f = 0; f < F_INPUT; ++f) xs += xLds[m * 8 + f] * wx5[f];
          MnB[m * 48 + g] = f2bf(xs);
        }
      }
      __syncthreads();
      {
        int k = tid >> 4, rr = tid & 15;
        m1[(size_t)k * N_NODES + row0 + rr] = MnB[rr * 48 + k];
      }
      __threadfence();
    }

    grid.sync();

    unsigned short* tmp = m0; m0 = m1; m1 = m2; m2 = tmp;
  }

  // ---- epilogue: out = h_final @ Wfc^T + b_fc (fp32 h, as in verified kernel) ----
  if (tid < 16) {
    float s = b_fc[0];
#pragma unroll
    for (int k = 0; k < 32; ++k) s += gatesLds[tid * 132 + k];
    out[row0 + tid] = s;
  }
}

extern "C" void kernel_launch(void* const* d_in, const int* in_sizes, int n_in,
                              void* d_out, int out_size, void* d_ws, size_t ws_size,
                              hipStream_t stream) {
  (void)in_sizes; (void)n_in; (void)out_size; (void)ws_size;
  const float* X   = (const float*)d_in[0];
  const float* A   = (const float*)d_in[1];
  const float* Wx  = (const float*)d_in[2];
  const float* Wh  = (const float*)d_in[3];
  const float* Wc  = (const float*)d_in[4];
  const float* Wih = (const float*)d_in[5];
  const float* Whh = (const float*)d_in[6];
  const float* bih = (const float*)d_in[7];
  const float* bhh = (const float*)d_in[8];
  const float* Wfc = (const float*)d_in[9];
  const float* bfc = (const float*)d_in[10];
  float* outp = (float*)d_out;

  char* ws = (char*)d_ws;
  unsigned short* b0 = (unsigned short*)ws; ws += (size_t)N_NODES * H_DIM * 2;
  unsigned short* b1 = (unsigned short*)ws; ws += (size_t)N_NODES * H_DIM * 2;
  unsigned short* b2 = (unsigned short*)ws; ws += (size_t)N_NODES * H_DIM * 2;

  void* args[] = {
    (void*)&A, (void*)&X, (void*)&Wx, (void*)&Wh, (void*)&Wc,
    (void*)&Wih, (void*)&Whh, (void*)&bih, (void*)&bhh,
    (void*)&Wfc, (void*)&bfc, (void*)&outp,
    (void*)&b0, (void*)&b1, (void*)&b2
  };
  hipLaunchCooperativeKernel((const void*)k_roll, dim3(256), dim3(512),
                             args, 0, stream);
}

// Round 3
// 3097.101 us; speedup vs baseline: 5.3666x; 5.3666x over previous
//
#include <hip/hip_runtime.h>

#define N_NODES 4096
#define H_DIM 32
#define F_INPUT 5
#define ROLLS 200
#define NBLK 256

typedef __attribute__((ext_vector_type(8))) short bf16x8;
typedef __attribute__((ext_vector_type(4))) float fx4;

__device__ __forceinline__ unsigned short f2bf(float f) {
  unsigned int u = __builtin_bit_cast(unsigned int, f);
  u += 0x7fffu + ((u >> 16) & 1u);   // round-to-nearest-even (inputs are benign, no NaN/inf)
  return (unsigned short)(u >> 16);
}

// Flag barrier: Mt already stored via agent-scope atomics. Drain store-acks,
// publish epoch, poll all 256 block flags (wave 0, 4/lane, L2-bypassing
// loads), then acquire-invalidate so cached Mt reads see fresh data.
__device__ __forceinline__ void barrier_sync(unsigned* flags, int bid,
                                             unsigned target, int tid) {
  asm volatile("s_waitcnt vmcnt(0)" ::: "memory");
  __syncthreads();   // all waves' agent stores acked at coherence point
  if (tid == 0)
    __hip_atomic_store(&flags[bid], target, __ATOMIC_RELAXED,
                       __HIP_MEMORY_SCOPE_AGENT);
  if (tid < 64) {
    for (;;) {
      bool ok = true;
#pragma unroll
      for (int j = 0; j < 4; ++j) {
        unsigned v = __hip_atomic_load(&flags[tid * 4 + j], __ATOMIC_RELAXED,
                                       __HIP_MEMORY_SCOPE_AGENT);
        ok = ok && (v >= target);
      }
      if (__ballot(ok) == ~0ull) break;
      __builtin_amdgcn_s_sleep(1);
    }
    // tag-invalidate L1 (per-CU) + L2 (per-XCD) so subsequent plain loads
    // refetch fresh Mt; caches are shared, one wave's fence covers the block
    __builtin_amdgcn_fence(__ATOMIC_ACQUIRE, "agent");
  }
  __syncthreads();
}

// store a 16x32 bf16 LDS tile (A-frag layout, stride 48) transposed into
// Mt[k][row0+r] via agent-scope uint stores (cross-XCD visible, no fence)
__device__ __forceinline__ void store_mt_agent(unsigned short* mt, int row0,
                                               const unsigned short* tile,
                                               int tid) {
  if (tid < 256) {
    int k = tid >> 3, rp = tid & 7;          // k 0..31, row-pair 0..7
    unsigned lo = tile[(rp * 2) * 48 + k];
    unsigned hi = tile[(rp * 2 + 1) * 48 + k];
    unsigned val = lo | (hi << 16);
    unsigned* dst = (unsigned*)(mt + (size_t)k * N_NODES + row0) + rp;
    __hip_atomic_store(dst, val, __ATOMIC_RELAXED, __HIP_MEMORY_SCOPE_AGENT);
  }
}

// Persistent cooperative kernel, hand-rolled barrier (no grid.sync).
// grid = 256 blocks (1/CU), block = 512 threads (8 waves), 16 rows/block.
// A lives in VGPRs; h/c in LDS; Mt triple-buffered in global, 1 barrier/step.
__global__ __launch_bounds__(512, 2) void k_roll(
    const float* __restrict__ A, const float* __restrict__ X,
    const float* __restrict__ Wx, const float* __restrict__ Wh, const float* __restrict__ Wc,
    const float* __restrict__ Wih, const float* __restrict__ Whh,
    const float* __restrict__ b_ih, const float* __restrict__ b_hh,
    const float* __restrict__ Wfc, const float* __restrict__ b_fc,
    float* __restrict__ out,
    unsigned short* __restrict__ buf0, unsigned short* __restrict__ buf1,
    unsigned short* __restrict__ buf2, unsigned* __restrict__ flags) {

  __shared__ __align__(16) float red[8 * 16 * 33];          // split-K partials (pad 33)
  __shared__ __align__(16) unsigned short inpB[16 * 48];    // inp bf16, A-frag layout
  __shared__ __align__(16) unsigned short hB[16 * 48];      // persistent h (bf16 frag)
  __shared__ __align__(16) unsigned short cnB[16 * 48];     // c_new bf16 (for M_next)
  __shared__ __align__(16) unsigned short MnB[16 * 48];
  __shared__ __align__(16) float cB[16 * 32];               // persistent c (fp32)
  __shared__ __align__(16) float gatesLds[16 * 132];
  __shared__ __align__(16) float xLds[16 * 8];

  const int tid  = threadIdx.x;
  const int wave = tid >> 6;        // 0..7
  const int lane = tid & 63;
  const int l15  = lane & 15;
  const int quad = lane >> 4;       // 0..3
  const int bid  = blockIdx.x;
  const int row0 = bid << 4;

  // ---- prologue: A fragments fp32->bf16 into VGPRs (once) ----
  bf16x8 areg[16];
  {
    const float* Ap = A + (size_t)(row0 + l15) * N_NODES + wave * 512 + quad * 8;
#pragma unroll
    for (int kk = 0; kk < 16; ++kk) {
      bf16x8 a;
#pragma unroll
      for (int j = 0; j < 8; ++j) a[j] = (short)f2bf(Ap[kk * 32 + j]);
      areg[kk] = a;
    }
  }

  // gate weight fragments: wave w owns gate cols [16w, 16w+16)
  const int g = (wave << 4) + l15;
  bf16x8 bI, bH;
#pragma unroll
  for (int j = 0; j < 8; ++j) {
    bI[j] = (short)f2bf(Wih[g * 32 + quad * 8 + j]);
    bH[j] = (short)f2bf(Whh[g * 32 + quad * 8 + j]);
  }
  const float bias = b_ih[g] + b_hh[g];

  // M_next weight fragments (waves 0,1 only): WhT[n][k]=Wh[k][n]
  bf16x8 bWh, bWc;
  float wx5[F_INPUT];
  if (wave < 2) {
#pragma unroll
    for (int j = 0; j < 8; ++j) {
      bWh[j] = (short)f2bf(Wh[(quad * 8 + j) * H_DIM + g]);
      bWc[j] = (short)f2bf(Wc[(quad * 8 + j) * H_DIM + g]);
    }
#pragma unroll
    for (int f = 0; f < F_INPUT; ++f) wx5[f] = Wx[f * H_DIM + g];
  }

  // h = c = 0 ; Mt0 = (x0 @ Wx)^T staged in LDS
  {
    int r = tid >> 5, k = tid & 31;
    hB[r * 48 + k] = 0;       // f2bf(0)==0
    cB[r * 32 + k] = 0.f;
    float s = 0.f;
#pragma unroll
    for (int f = 0; f < F_INPUT; ++f)
      s += X[(size_t)(row0 + r) * F_INPUT + f] * Wx[f * H_DIM + k];
    MnB[r * 48 + k] = f2bf(s);
  }
  __syncthreads();
  store_mt_agent(buf0, row0, MnB, tid);
  barrier_sync(flags, bid, 1u, tid);

  unsigned short* m0 = buf0;   // read at step t
  unsigned short* m1 = buf1;   // written at step t
  unsigned short* m2 = buf2;   // idle at step t

  for (int t = 0; t < ROLLS; ++t) {
    // ---- phase A: split-K MFMA inp(16x32) = A(16x4096) @ M(4096x32) ----
    fx4 acc0 = {0.f, 0.f, 0.f, 0.f}, acc1 = {0.f, 0.f, 0.f, 0.f};
    {
      const unsigned short* B0 = m0 + (size_t)l15 * N_NODES + wave * 512 + quad * 8;
      const unsigned short* B1 = B0 + (size_t)16 * N_NODES;
#pragma unroll
      for (int kk = 0; kk < 16; ++kk) {
        bf16x8 b0 = *(const bf16x8*)(B0 + kk * 32);
        bf16x8 b1 = *(const bf16x8*)(B1 + kk * 32);
        acc0 = __builtin_amdgcn_mfma_f32_16x16x32_bf16(areg[kk], b0, acc0, 0, 0, 0);
        acc1 = __builtin_amdgcn_mfma_f32_16x16x32_bf16(areg[kk], b1, acc1, 0, 0, 0);
      }
    }
#pragma unroll
    for (int r = 0; r < 4; ++r) {
      red[(wave * 16 + quad * 4 + r) * 33 + l15]      = acc0[r];
      red[(wave * 16 + quad * 4 + r) * 33 + 16 + l15] = acc1[r];
    }
    __syncthreads();

    // ---- phase B: reduce 8 partials -> inp bf16 ; stage x_{t+1} ----
    {
      int m = tid >> 5, n = tid & 31;
      float s = 0.f;
#pragma unroll
      for (int w = 0; w < 8; ++w) s += red[(w * 16 + m) * 33 + n];
      inpB[m * 48 + n] = f2bf(s);
    }
    if (t + 1 < ROLLS && tid < 128) {
      int r = tid >> 3, f = tid & 7;
      if (f < F_INPUT)
        xLds[r * 8 + f] = X[(size_t)(t + 1) * N_NODES * F_INPUT +
                            (size_t)(row0 + r) * F_INPUT + f];
    }
    __syncthreads();

    // ---- phase C: gates(16x128) = inp@Wih^T + h@Whh^T + b ----
    {
      bf16x8 aI = *(const bf16x8*)(inpB + l15 * 48 + quad * 8);
      bf16x8 aH = *(const bf16x8*)(hB   + l15 * 48 + quad * 8);
      fx4 gacc = {0.f, 0.f, 0.f, 0.f};
      gacc = __builtin_amdgcn_mfma_f32_16x16x32_bf16(aI, bI, gacc, 0, 0, 0);
      gacc = __builtin_amdgcn_mfma_f32_16x16x32_bf16(aH, bH, gacc, 0, 0, 0);
#pragma unroll
      for (int r = 0; r < 4; ++r) gatesLds[(quad * 4 + r) * 132 + g] = gacc[r] + bias;
    }
    __syncthreads();

    // ---- phase D: LSTM cell elementwise (fp32 state in LDS) ----
    {
      int r = tid >> 5, k = tid & 31;
      float gi = gatesLds[r * 132 + k];
      float gf = gatesLds[r * 132 + 32 + k];
      float gg = gatesLds[r * 132 + 64 + k];
      float go = gatesLds[r * 132 + 96 + k];
      float i_ = 1.f / (1.f + __expf(-gi));
      float f_ = 1.f / (1.f + __expf(-gf));
      float g_ = tanhf(gg);
      float o_ = 1.f / (1.f + __expf(-go));
      float cn = f_ * cB[r * 32 + k] + i_ * g_;
      float hn = o_ * tanhf(cn);
      cB[r * 32 + k] = cn;
      hB[r * 48 + k] = f2bf(hn);        // next step's h fragment
      cnB[r * 48 + k] = f2bf(cn);
      if (t == ROLLS - 1) gatesLds[r * 132 + k] = hn * Wfc[k];
    }
    __syncthreads();

    // ---- phase E: M_next = h@Wh + c@Wc + x@Wx (waves 0,1), agent store ----
    if (t < ROLLS - 1) {
      if (wave < 2) {
        bf16x8 aH = *(const bf16x8*)(hB  + l15 * 48 + quad * 8);
        bf16x8 aC = *(const bf16x8*)(cnB + l15 * 48 + quad * 8);
        fx4 m4 = {0.f, 0.f, 0.f, 0.f};
        m4 = __builtin_amdgcn_mfma_f32_16x16x32_bf16(aH, bWh, m4, 0, 0, 0);
        m4 = __builtin_amdgcn_mfma_f32_16x16x32_bf16(aC, bWc, m4, 0, 0, 0);
#pragma unroll
        for (int r = 0; r < 4; ++r) {
          int m = quad * 4 + r;
          float xs = m4[r];
#pragma unroll
          for (int f = 0; f < F_INPUT; ++f) xs += xLds[m * 8 + f] * wx5[f];
          MnB[m * 48 + g] = f2bf(xs);
        }
      }
      __syncthreads();
      store_mt_agent(m1, row0, MnB, tid);
      barrier_sync(flags, bid, (unsigned)(t + 2), tid);
    }

    unsigned short* tmp = m0; m0 = m1; m1 = m2; m2 = tmp;
  }

  // ---- epilogue: out = h_final @ Wfc^T + b_fc ----
  if (tid < 16) {
    float s = b_fc[0];
#pragma unroll
    for (int k = 0; k < 32; ++k) s += gatesLds[tid * 132 + k];
    out[row0 + tid] = s;
  }
}

extern "C" void kernel_launch(void* const* d_in, const int* in_sizes, int n_in,
                              void* d_out, int out_size, void* d_ws, size_t ws_size,
                              hipStream_t stream) {
  (void)in_sizes; (void)n_in; (void)out_size; (void)ws_size;
  const float* X   = (const float*)d_in[0];
  const float* A   = (const float*)d_in[1];
  const float* Wx  = (const float*)d_in[2];
  const float* Wh  = (const float*)d_in[3];
  const float* Wc  = (const float*)d_in[4];
  const float* Wih = (const float*)d_in[5];
  const float* Whh = (const float*)d_in[6];
  const float* bih = (const float*)d_in[7];
  const float* bhh = (const float*)d_in[8];
  const float* Wfc = (const float*)d_in[9];
  const float* bfc = (const float*)d_in[10];
  float* outp = (float*)d_out;

  char* ws = (char*)d_ws;
  unsigned short* b0 = (unsigned short*)ws; ws += (size_t)N_NODES * H_DIM * 2;
  unsigned short* b1 = (unsigned short*)ws; ws += (size_t)N_NODES * H_DIM * 2;
  unsigned short* b2 = (unsigned short*)ws; ws += (size_t)N_NODES * H_DIM * 2;
  unsigned* flags    = (unsigned*)ws;       ws += NBLK * sizeof(unsigned);

  // epoch flags must start at 0 every call (graph-capturable async memset)
  (void)hipMemsetAsync(flags, 0, NBLK * sizeof(unsigned), stream);

  void* args[] = {
    (void*)&A, (void*)&X, (void*)&Wx, (void*)&Wh, (void*)&Wc,
    (void*)&Wih, (void*)&Whh, (void*)&bih, (void*)&bhh,
    (void*)&Wfc, (void*)&bfc, (void*)&outp,
    (void*)&b0, (void*)&b1, (void*)&b2, (void*)&flags
  };
  (void)hipLaunchCooperativeKernel((const void*)k_roll, dim3(NBLK), dim3(512),
                                   args, 0, stream);
}

// Round 4
// 2720.226 us; speedup vs baseline: 6.1101x; 1.1385x over previous
//
#include <hip/hip_runtime.h>

#define N_NODES 4096
#define H_DIM 32
#define F_INPUT 5
#define ROLLS 200
#define NBLK 256
#define NBUF 64                          // Mt ring: write-once per 64 steps
#define MT_ELEMS ((size_t)H_DIM * N_NODES)   // 131072 shorts = 256 KiB

typedef __attribute__((ext_vector_type(8))) short bf16x8;
typedef __attribute__((ext_vector_type(4))) float fx4;

__device__ __forceinline__ unsigned short f2bf(float f) {
  unsigned int u = __builtin_bit_cast(unsigned int, f);
  u += 0x7fffu + ((u >> 16) & 1u);   // round-to-nearest-even (inputs are benign, no NaN/inf)
  return (unsigned short)(u >> 16);
}

// Flag barrier: Mt already stored via agent-scope (write-through) stores.
// Drain store-acks, publish epoch, wave 0 polls all 256 block flags with
// L2-bypassing loads. Acquire-invalidate only when `inv` (every NBUF steps):
// buffers are write-once within a window, so cached Mt reads are fresh by
// construction and XCD-level L2 sharing of Mt stays intact.
__device__ __forceinline__ void barrier_sync(unsigned* flags, int bid,
                                             unsigned target, int tid,
                                             bool inv) {
  asm volatile("s_waitcnt vmcnt(0)" ::: "memory");
  __syncthreads();   // all waves' agent stores acked at coherence point
  if (tid == 0)
    __hip_atomic_store(&flags[bid], target, __ATOMIC_RELAXED,
                       __HIP_MEMORY_SCOPE_AGENT);
  if (tid < 64) {
    for (;;) {
      bool ok = true;
#pragma unroll
      for (int j = 0; j < 4; ++j) {
        unsigned v = __hip_atomic_load(&flags[tid * 4 + j], __ATOMIC_RELAXED,
                                       __HIP_MEMORY_SCOPE_AGENT);
        ok = ok && (v >= target);
      }
      if (__ballot(ok) == ~0ull) break;
      __builtin_amdgcn_s_sleep(1);
    }
    if (inv)
      __builtin_amdgcn_fence(__ATOMIC_ACQUIRE, "agent");  // L1+L2 tag inv
  }
  __syncthreads();
}

// store a 16x32 bf16 LDS tile (A-frag layout, stride 48) transposed into
// Mt[k][row0+r] via agent-scope uint stores (cross-XCD visible, no fence)
__device__ __forceinline__ void store_mt_agent(unsigned short* mt, int row0,
                                               const unsigned short* tile,
                                               int tid) {
  if (tid < 256) {
    int k = tid >> 3, rp = tid & 7;          // k 0..31, row-pair 0..7
    unsigned lo = tile[(rp * 2) * 48 + k];
    unsigned hi = tile[(rp * 2 + 1) * 48 + k];
    unsigned val = lo | (hi << 16);
    unsigned* dst = (unsigned*)(mt + (size_t)k * N_NODES + row0) + rp;
    __hip_atomic_store(dst, val, __ATOMIC_RELAXED, __HIP_MEMORY_SCOPE_AGENT);
  }
}

// Persistent cooperative kernel, hand-rolled barrier (no grid.sync).
// grid = 256 blocks (1/CU), block = 512 threads (8 waves), 16 rows/block.
// A lives in VGPRs; h/c in LDS; Mt ring-buffered (64) in global, 1 barrier/step.
__global__ __launch_bounds__(512, 2) void k_roll(
    const float* __restrict__ A, const float* __restrict__ X,
    const float* __restrict__ Wx, const float* __restrict__ Wh, const float* __restrict__ Wc,
    const float* __restrict__ Wih, const float* __restrict__ Whh,
    const float* __restrict__ b_ih, const float* __restrict__ b_hh,
    const float* __restrict__ Wfc, const float* __restrict__ b_fc,
    float* __restrict__ out,
    unsigned short* __restrict__ bufs, unsigned* __restrict__ flags) {

  __shared__ __align__(16) float red[8 * 16 * 33];          // split-K partials (pad 33)
  __shared__ __align__(16) unsigned short inpB[16 * 48];    // inp bf16, A-frag layout
  __shared__ __align__(16) unsigned short hB[16 * 48];      // persistent h (bf16 frag)
  __shared__ __align__(16) unsigned short cnB[16 * 48];     // c_new bf16 (for M_next)
  __shared__ __align__(16) unsigned short MnB[16 * 48];
  __shared__ __align__(16) float cB[16 * 32];               // persistent c (fp32)
  __shared__ __align__(16) float gatesLds[16 * 132];
  __shared__ __align__(16) float xLds[16 * 8];

  const int tid  = threadIdx.x;
  const int wave = tid >> 6;        // 0..7
  const int lane = tid & 63;
  const int l15  = lane & 15;
  const int quad = lane >> 4;       // 0..3
  const int bid  = blockIdx.x;
  const int row0 = bid << 4;

  // ---- prologue: A fragments fp32->bf16 into VGPRs (once) ----
  bf16x8 areg[16];
  {
    const float* Ap = A + (size_t)(row0 + l15) * N_NODES + wave * 512 + quad * 8;
#pragma unroll
    for (int kk = 0; kk < 16; ++kk) {
      bf16x8 a;
#pragma unroll
      for (int j = 0; j < 8; ++j) a[j] = (short)f2bf(Ap[kk * 32 + j]);
      areg[kk] = a;
    }
  }

  // gate weight fragments: wave w owns gate cols [16w, 16w+16)
  const int g = (wave << 4) + l15;
  bf16x8 bI, bH;
#pragma unroll
  for (int j = 0; j < 8; ++j) {
    bI[j] = (short)f2bf(Wih[g * 32 + quad * 8 + j]);
    bH[j] = (short)f2bf(Whh[g * 32 + quad * 8 + j]);
  }
  const float bias = b_ih[g] + b_hh[g];

  // M_next weight fragments (waves 0,1 only): WhT[n][k]=Wh[k][n]
  bf16x8 bWh, bWc;
  float wx5[F_INPUT];
  if (wave < 2) {
#pragma unroll
    for (int j = 0; j < 8; ++j) {
      bWh[j] = (short)f2bf(Wh[(quad * 8 + j) * H_DIM + g]);
      bWc[j] = (short)f2bf(Wc[(quad * 8 + j) * H_DIM + g]);
    }
#pragma unroll
    for (int f = 0; f < F_INPUT; ++f) wx5[f] = Wx[f * H_DIM + g];
  }

  // h = c = 0 ; Mt0 = (x0 @ Wx)^T staged in LDS
  {
    int r = tid >> 5, k = tid & 31;
    hB[r * 48 + k] = 0;       // f2bf(0)==0
    cB[r * 32 + k] = 0.f;
    float s = 0.f;
#pragma unroll
    for (int f = 0; f < F_INPUT; ++f)
      s += X[(size_t)(row0 + r) * F_INPUT + f] * Wx[f * H_DIM + k];
    MnB[r * 48 + k] = f2bf(s);
  }
  __syncthreads();
  store_mt_agent(bufs, row0, MnB, tid);      // buffer 0
  barrier_sync(flags, bid, 1u, tid, true);   // clear any pre-existing lines

  for (int t = 0; t < ROLLS; ++t) {
    const unsigned short* m0 = bufs + (size_t)(t & (NBUF - 1)) * MT_ELEMS;
    unsigned short* m1 = bufs + (size_t)((t + 1) & (NBUF - 1)) * MT_ELEMS;

    // ---- phase A: split-K MFMA inp(16x32) = A(16x4096) @ M(4096x32) ----
    fx4 acc0 = {0.f, 0.f, 0.f, 0.f}, acc1 = {0.f, 0.f, 0.f, 0.f};
    {
      const unsigned short* B0 = m0 + (size_t)l15 * N_NODES + wave * 512 + quad * 8;
      const unsigned short* B1 = B0 + (size_t)16 * N_NODES;
#pragma unroll
      for (int kk = 0; kk < 16; ++kk) {
        bf16x8 b0 = *(const bf16x8*)(B0 + kk * 32);
        bf16x8 b1 = *(const bf16x8*)(B1 + kk * 32);
        acc0 = __builtin_amdgcn_mfma_f32_16x16x32_bf16(areg[kk], b0, acc0, 0, 0, 0);
        acc1 = __builtin_amdgcn_mfma_f32_16x16x32_bf16(areg[kk], b1, acc1, 0, 0, 0);
      }
    }
#pragma unroll
    for (int r = 0; r < 4; ++r) {
      red[(wave * 16 + quad * 4 + r) * 33 + l15]      = acc0[r];
      red[(wave * 16 + quad * 4 + r) * 33 + 16 + l15] = acc1[r];
    }
    __syncthreads();

    // ---- phase B: reduce 8 partials -> inp bf16 ; stage x_{t+1} ----
    {
      int m = tid >> 5, n = tid & 31;
      float s = 0.f;
#pragma unroll
      for (int w = 0; w < 8; ++w) s += red[(w * 16 + m) * 33 + n];
      inpB[m * 48 + n] = f2bf(s);
    }
    if (t + 1 < ROLLS && tid < 128) {
      int r = tid >> 3, f = tid & 7;
      if (f < F_INPUT)
        xLds[r * 8 + f] = X[(size_t)(t + 1) * N_NODES * F_INPUT +
                            (size_t)(row0 + r) * F_INPUT + f];
    }
    __syncthreads();

    // ---- phase C: gates(16x128) = inp@Wih^T + h@Whh^T + b ----
    {
      bf16x8 aI = *(const bf16x8*)(inpB + l15 * 48 + quad * 8);
      bf16x8 aH = *(const bf16x8*)(hB   + l15 * 48 + quad * 8);
      fx4 gacc = {0.f, 0.f, 0.f, 0.f};
      gacc = __builtin_amdgcn_mfma_f32_16x16x32_bf16(aI, bI, gacc, 0, 0, 0);
      gacc = __builtin_amdgcn_mfma_f32_16x16x32_bf16(aH, bH, gacc, 0, 0, 0);
#pragma unroll
      for (int r = 0; r < 4; ++r) gatesLds[(quad * 4 + r) * 132 + g] = gacc[r] + bias;
    }
    __syncthreads();

    // ---- phase D: LSTM cell elementwise (fp32 state in LDS) ----
    {
      int r = tid >> 5, k = tid & 31;
      float gi = gatesLds[r * 132 + k];
      float gf = gatesLds[r * 132 + 32 + k];
      float gg = gatesLds[r * 132 + 64 + k];
      float go = gatesLds[r * 132 + 96 + k];
      float i_ = 1.f / (1.f + __expf(-gi));
      float f_ = 1.f / (1.f + __expf(-gf));
      float g_ = tanhf(gg);
      float o_ = 1.f / (1.f + __expf(-go));
      float cn = f_ * cB[r * 32 + k] + i_ * g_;
      float hn = o_ * tanhf(cn);
      cB[r * 32 + k] = cn;
      hB[r * 48 + k] = f2bf(hn);        // next step's h fragment
      cnB[r * 48 + k] = f2bf(cn);
      if (t == ROLLS - 1) gatesLds[r * 132 + k] = hn * Wfc[k];
    }
    __syncthreads();

    // ---- phase E: M_next = h@Wh + c@Wc + x@Wx (waves 0,1), agent store ----
    if (t < ROLLS - 1) {
      if (wave < 2) {
        bf16x8 aH = *(const bf16x8*)(hB  + l15 * 48 + quad * 8);
        bf16x8 aC = *(const bf16x8*)(cnB + l15 * 48 + quad * 8);
        fx4 m4 = {0.f, 0.f, 0.f, 0.f};
        m4 = __builtin_amdgcn_mfma_f32_16x16x32_bf16(aH, bWh, m4, 0, 0, 0);
        m4 = __builtin_amdgcn_mfma_f32_16x16x32_bf16(aC, bWc, m4, 0, 0, 0);
#pragma unroll
        for (int r = 0; r < 4; ++r) {
          int m = quad * 4 + r;
          float xs = m4[r];
#pragma unroll
          for (int f = 0; f < F_INPUT; ++f) xs += xLds[m * 8 + f] * wx5[f];
          MnB[m * 48 + g] = f2bf(xs);
        }
      }
      __syncthreads();
      store_mt_agent(m1, row0, MnB, tid);
      // fence only when the ring wraps (buffer reuse): t+1 = 64, 128, 192
      barrier_sync(flags, bid, (unsigned)(t + 2), tid,
                   ((t + 1) & (NBUF - 1)) == 0);
    }
  }

  // ---- epilogue: out = h_final @ Wfc^T + b_fc ----
  if (tid < 16) {
    float s = b_fc[0];
#pragma unroll
    for (int k = 0; k < 32; ++k) s += gatesLds[tid * 132 + k];
    out[row0 + tid] = s;
  }
}

extern "C" void kernel_launch(void* const* d_in, const int* in_sizes, int n_in,
                              void* d_out, int out_size, void* d_ws, size_t ws_size,
                              hipStream_t stream) {
  (void)in_sizes; (void)n_in; (void)out_size; (void)ws_size;
  const float* X   = (const float*)d_in[0];
  const float* A   = (const float*)d_in[1];
  const float* Wx  = (const float*)d_in[2];
  const float* Wh  = (const float*)d_in[3];
  const float* Wc  = (const float*)d_in[4];
  const float* Wih = (const float*)d_in[5];
  const float* Whh = (const float*)d_in[6];
  const float* bih = (const float*)d_in[7];
  const float* bhh = (const float*)d_in[8];
  const float* Wfc = (const float*)d_in[9];
  const float* bfc = (const float*)d_in[10];
  float* outp = (float*)d_out;

  char* ws = (char*)d_ws;
  unsigned short* bufs = (unsigned short*)ws;
  ws += (size_t)NBUF * MT_ELEMS * 2;           // 16 MiB Mt ring
  unsigned* flags = (unsigned*)ws;
  ws += NBLK * sizeof(unsigned);

  // epoch flags must start at 0 every call (graph-capturable async memset)
  (void)hipMemsetAsync(flags, 0, NBLK * sizeof(unsigned), stream);

  void* args[] = {
    (void*)&A, (void*)&X, (void*)&Wx, (void*)&Wh, (void*)&Wc,
    (void*)&Wih, (void*)&Whh, (void*)&bih, (void*)&bhh,
    (void*)&Wfc, (void*)&bfc, (void*)&outp,
    (void*)&bufs, (void*)&flags
  };
  (void)hipLaunchCooperativeKernel((const void*)k_roll, dim3(NBLK), dim3(512),
                                   args, 0, stream);
}

// Round 5
// 2592.325 us; speedup vs baseline: 6.4115x; 1.0493x over previous
//
#include <hip/hip_runtime.h>

#define N_NODES 4096
#define H_DIM 32
#define F_INPUT 5
#define ROLLS 200
#define NBLK 256
#define NBUF 64                          // Mt ring: write-once per 64 steps
#define MT_ELEMS ((size_t)H_DIM * N_NODES)   // 131072 shorts = 256 KiB

typedef __attribute__((ext_vector_type(8))) short bf16x8;
typedef __attribute__((ext_vector_type(4))) float fx4;

__device__ __forceinline__ unsigned short f2bf(float f) {
  unsigned int u = __builtin_bit_cast(unsigned int, f);
  u += 0x7fffu + ((u >> 16) & 1u);   // round-to-nearest-even (inputs are benign, no NaN/inf)
  return (unsigned short)(u >> 16);
}

// producer side: drain this block's agent-scope Mt stores to the coherence
// point, then publish the epoch flag (agent scope, L2-bypassing).
__device__ __forceinline__ void publish(unsigned* flags, int bid,
                                        unsigned target, int tid) {
  asm volatile("s_waitcnt vmcnt(0)" ::: "memory");
  __syncthreads();   // all waves' Mt stores acked
  if (tid == 0)
    __hip_atomic_store(&flags[bid], target, __ATOMIC_RELAXED,
                       __HIP_MEMORY_SCOPE_AGENT);
}

// consumer side: wave w consumes Mt K-chunk [512w,512w+512) produced by
// blocks 32w..32w+31 — wait on exactly those 32 flags (1/lane, lanes 32-63
// duplicate). No full-grid rendezvous: each wave starts as soon as ITS
// producers are done; drift across blocks is bounded by 1 step since the
// union of the 8 groups covers all 256 blocks.
__device__ __forceinline__ void wait_group(const unsigned* flags, int wave,
                                           int lane, unsigned target) {
  const unsigned* f = flags + (wave << 5) + (lane & 31);
  for (;;) {
    unsigned v = __hip_atomic_load(f, __ATOMIC_RELAXED,
                                   __HIP_MEMORY_SCOPE_AGENT);
    if (__ballot(v >= target) == ~0ull) break;
    __builtin_amdgcn_s_sleep(1);
  }
  asm volatile("" ::: "memory");   // keep Mt loads below the wait
}

// store a 16x32 bf16 LDS tile (A-frag layout, stride 48) transposed into
// Mt[k][row0+r] via agent-scope uint stores (cross-XCD visible, no fence)
__device__ __forceinline__ void store_mt_agent(unsigned short* mt, int row0,
                                               const unsigned short* tile,
                                               int tid) {
  if (tid < 256) {
    int k = tid >> 3, rp = tid & 7;          // k 0..31, row-pair 0..7
    unsigned lo = tile[(rp * 2) * 48 + k];
    unsigned hi = tile[(rp * 2 + 1) * 48 + k];
    unsigned val = lo | (hi << 16);
    unsigned* dst = (unsigned*)(mt + (size_t)k * N_NODES + row0) + rp;
    __hip_atomic_store(dst, val, __ATOMIC_RELAXED, __HIP_MEMORY_SCOPE_AGENT);
  }
}

// Persistent cooperative kernel, async dataflow (per-wave producer waits).
// grid = 256 blocks (1/CU), block = 512 threads (8 waves), 16 rows/block.
// A lives in VGPRs; h/c in LDS; Mt ring-buffered (64) in global.
__global__ __launch_bounds__(512, 2) void k_roll(
    const float* __restrict__ A, const float* __restrict__ X,
    const float* __restrict__ Wx, const float* __restrict__ Wh, const float* __restrict__ Wc,
    const float* __restrict__ Wih, const float* __restrict__ Whh,
    const float* __restrict__ b_ih, const float* __restrict__ b_hh,
    const float* __restrict__ Wfc, const float* __restrict__ b_fc,
    float* __restrict__ out,
    unsigned short* __restrict__ bufs, unsigned* __restrict__ flags) {

  __shared__ __align__(16) float red[8 * 16 * 33];          // split-K partials (pad 33)
  __shared__ __align__(16) unsigned short inpB[16 * 48];    // inp bf16, A-frag layout
  __shared__ __align__(16) unsigned short hB[16 * 48];      // persistent h (bf16 frag)
  __shared__ __align__(16) unsigned short cnB[16 * 48];     // c_new bf16 (for M_next)
  __shared__ __align__(16) unsigned short MnB[16 * 48];
  __shared__ __align__(16) float cB[16 * 32];               // persistent c (fp32)
  __shared__ __align__(16) float gatesLds[16 * 132];
  __shared__ __align__(16) float xLds[16 * 8];

  const int tid  = threadIdx.x;
  const int wave = tid >> 6;        // 0..7
  const int lane = tid & 63;
  const int l15  = lane & 15;
  const int quad = lane >> 4;       // 0..3
  const int bid  = blockIdx.x;
  const int row0 = bid << 4;

  // ---- prologue: A fragments fp32->bf16 into VGPRs (once) ----
  bf16x8 areg[16];
  {
    const float* Ap = A + (size_t)(row0 + l15) * N_NODES + wave * 512 + quad * 8;
#pragma unroll
    for (int kk = 0; kk < 16; ++kk) {
      bf16x8 a;
#pragma unroll
      for (int j = 0; j < 8; ++j) a[j] = (short)f2bf(Ap[kk * 32 + j]);
      areg[kk] = a;
    }
  }

  // gate weight fragments: wave w owns gate cols [16w, 16w+16)
  const int g = (wave << 4) + l15;
  bf16x8 bI, bH;
#pragma unroll
  for (int j = 0; j < 8; ++j) {
    bI[j] = (short)f2bf(Wih[g * 32 + quad * 8 + j]);
    bH[j] = (short)f2bf(Whh[g * 32 + quad * 8 + j]);
  }
  const float bias = b_ih[g] + b_hh[g];

  // M_next weight fragments (waves 0,1 only): WhT[n][k]=Wh[k][n]
  bf16x8 bWh, bWc;
  float wx5[F_INPUT];
  if (wave < 2) {
#pragma unroll
    for (int j = 0; j < 8; ++j) {
      bWh[j] = (short)f2bf(Wh[(quad * 8 + j) * H_DIM + g]);
      bWc[j] = (short)f2bf(Wc[(quad * 8 + j) * H_DIM + g]);
    }
#pragma unroll
    for (int f = 0; f < F_INPUT; ++f) wx5[f] = Wx[f * H_DIM + g];
  }

  // h = c = 0 ; Mt0 = (x0 @ Wx)^T staged in LDS
  {
    int r = tid >> 5, k = tid & 31;
    hB[r * 48 + k] = 0;       // f2bf(0)==0
    cB[r * 32 + k] = 0.f;
    float s = 0.f;
#pragma unroll
    for (int f = 0; f < F_INPUT; ++f)
      s += X[(size_t)(row0 + r) * F_INPUT + f] * Wx[f * H_DIM + k];
    MnB[r * 48 + k] = f2bf(s);
  }
  __syncthreads();
  store_mt_agent(bufs, row0, MnB, tid);      // buffer 0
  publish(flags, bid, 1u, tid);

  for (int t = 0; t < ROLLS; ++t) {
    const unsigned short* m0 = bufs + (size_t)(t & (NBUF - 1)) * MT_ELEMS;
    unsigned short* m1 = bufs + (size_t)((t + 1) & (NBUF - 1)) * MT_ELEMS;

    // window wrap (t = 0,64,128,192): invalidate L1/L2 once so reused ring
    // buffers can't serve stale lines; also clears prior-call lines at t=0
    if ((t & (NBUF - 1)) == 0) {
      __syncthreads();
      if (tid < 64)
        __builtin_amdgcn_fence(__ATOMIC_ACQUIRE, "agent");
      __syncthreads();
    }

    // wait only for THIS wave's 32 producer blocks
    wait_group(flags, wave, lane, (unsigned)(t + 1));

    // ---- phase A: split-K MFMA inp(16x32) = A(16x4096) @ M(4096x32) ----
    fx4 acc0 = {0.f, 0.f, 0.f, 0.f}, acc1 = {0.f, 0.f, 0.f, 0.f};
    {
      const unsigned short* B0 = m0 + (size_t)l15 * N_NODES + wave * 512 + quad * 8;
      const unsigned short* B1 = B0 + (size_t)16 * N_NODES;
#pragma unroll
      for (int kk = 0; kk < 16; ++kk) {
        bf16x8 b0 = *(const bf16x8*)(B0 + kk * 32);
        bf16x8 b1 = *(const bf16x8*)(B1 + kk * 32);
        acc0 = __builtin_amdgcn_mfma_f32_16x16x32_bf16(areg[kk], b0, acc0, 0, 0, 0);
        acc1 = __builtin_amdgcn_mfma_f32_16x16x32_bf16(areg[kk], b1, acc1, 0, 0, 0);
      }
    }
#pragma unroll
    for (int r = 0; r < 4; ++r) {
      red[(wave * 16 + quad * 4 + r) * 33 + l15]      = acc0[r];
      red[(wave * 16 + quad * 4 + r) * 33 + 16 + l15] = acc1[r];
    }
    __syncthreads();

    // ---- phase B: reduce 8 partials -> inp bf16 ; stage x_{t+1} ----
    {
      int m = tid >> 5, n = tid & 31;
      float s = 0.f;
#pragma unroll
      for (int w = 0; w < 8; ++w) s += red[(w * 16 + m) * 33 + n];
      inpB[m * 48 + n] = f2bf(s);
    }
    if (t + 1 < ROLLS && tid < 128) {
      int r = tid >> 3, f = tid & 7;
      if (f < F_INPUT)
        xLds[r * 8 + f] = X[(size_t)(t + 1) * N_NODES * F_INPUT +
                            (size_t)(row0 + r) * F_INPUT + f];
    }
    __syncthreads();

    // ---- phase C: gates(16x128) = inp@Wih^T + h@Whh^T + b ----
    {
      bf16x8 aI = *(const bf16x8*)(inpB + l15 * 48 + quad * 8);
      bf16x8 aH = *(const bf16x8*)(hB   + l15 * 48 + quad * 8);
      fx4 gacc = {0.f, 0.f, 0.f, 0.f};
      gacc = __builtin_amdgcn_mfma_f32_16x16x32_bf16(aI, bI, gacc, 0, 0, 0);
      gacc = __builtin_amdgcn_mfma_f32_16x16x32_bf16(aH, bH, gacc, 0, 0, 0);
#pragma unroll
      for (int r = 0; r < 4; ++r) gatesLds[(quad * 4 + r) * 132 + g] = gacc[r] + bias;
    }
    __syncthreads();

    // ---- phase D: LSTM cell elementwise (fp32 state in LDS) ----
    {
      int r = tid >> 5, k = tid & 31;
      float gi = gatesLds[r * 132 + k];
      float gf = gatesLds[r * 132 + 32 + k];
      float gg = gatesLds[r * 132 + 64 + k];
      float go = gatesLds[r * 132 + 96 + k];
      float i_ = 1.f / (1.f + __expf(-gi));
      float f_ = 1.f / (1.f + __expf(-gf));
      float g_ = tanhf(gg);
      float o_ = 1.f / (1.f + __expf(-go));
      float cn = f_ * cB[r * 32 + k] + i_ * g_;
      float hn = o_ * tanhf(cn);
      cB[r * 32 + k] = cn;
      hB[r * 48 + k] = f2bf(hn);        // next step's h fragment
      cnB[r * 48 + k] = f2bf(cn);
      if (t == ROLLS - 1) gatesLds[r * 132 + k] = hn * Wfc[k];
    }
    __syncthreads();

    // ---- phase E: M_next = h@Wh + c@Wc + x@Wx (waves 0,1), agent store ----
    if (t < ROLLS - 1) {
      if (wave < 2) {
        bf16x8 aH = *(const bf16x8*)(hB  + l15 * 48 + quad * 8);
        bf16x8 aC = *(const bf16x8*)(cnB + l15 * 48 + quad * 8);
        fx4 m4 = {0.f, 0.f, 0.f, 0.f};
        m4 = __builtin_amdgcn_mfma_f32_16x16x32_bf16(aH, bWh, m4, 0, 0, 0);
        m4 = __builtin_amdgcn_mfma_f32_16x16x32_bf16(aC, bWc, m4, 0, 0, 0);
#pragma unroll
        for (int r = 0; r < 4; ++r) {
          int m = quad * 4 + r;
          float xs = m4[r];
#pragma unroll
          for (int f = 0; f < F_INPUT; ++f) xs += xLds[m * 8 + f] * wx5[f];
          MnB[m * 48 + g] = f2bf(xs);
        }
      }
      __syncthreads();
      store_mt_agent(m1, row0, MnB, tid);
      publish(flags, bid, (unsigned)(t + 2), tid);
    }
  }

  // ---- epilogue: out = h_final @ Wfc^T + b_fc ----
  if (tid < 16) {
    float s = b_fc[0];
#pragma unroll
    for (int k = 0; k < 32; ++k) s += gatesLds[tid * 132 + k];
    out[row0 + tid] = s;
  }
}

extern "C" void kernel_launch(void* const* d_in, const int* in_sizes, int n_in,
                              void* d_out, int out_size, void* d_ws, size_t ws_size,
                              hipStream_t stream) {
  (void)in_sizes; (void)n_in; (void)out_size; (void)ws_size;
  const float* X   = (const float*)d_in[0];
  const float* A   = (const float*)d_in[1];
  const float* Wx  = (const float*)d_in[2];
  const float* Wh  = (const float*)d_in[3];
  const float* Wc  = (const float*)d_in[4];
  const float* Wih = (const float*)d_in[5];
  const float* Whh = (const float*)d_in[6];
  const float* bih = (const float*)d_in[7];
  const float* bhh = (const float*)d_in[8];
  const float* Wfc = (const float*)d_in[9];
  const float* bfc = (const float*)d_in[10];
  float* outp = (float*)d_out;

  char* ws = (char*)d_ws;
  unsigned short* bufs = (unsigned short*)ws;
  ws += (size_t)NBUF * MT_ELEMS * 2;           // 16 MiB Mt ring
  unsigned* flags = (unsigned*)ws;
  ws += NBLK * sizeof(unsigned);

  // epoch flags must start at 0 every call (graph-capturable async memset)
  (void)hipMemsetAsync(flags, 0, NBLK * sizeof(unsigned), stream);

  void* args[] = {
    (void*)&A, (void*)&X, (void*)&Wx, (void*)&Wh, (void*)&Wc,
    (void*)&Wih, (void*)&Whh, (void*)&bih, (void*)&bhh,
    (void*)&Wfc, (void*)&bfc, (void*)&outp,
    (void*)&bufs, (void*)&flags
  };
  (void)hipLaunchCooperativeKernel((const void*)k_roll, dim3(NBLK), dim3(512),
                                   args, 0, stream);
}